// Round 1
// baseline (234.975 us; speedup 1.0000x reference)
//
#include <hip/hip_runtime.h>
#include <math.h>

namespace {
constexpr int NFACES = 384;
constexpr int IMG    = 256;
constexpr int CROP0  = 16;
constexpr int CROPN  = 224;
constexpr int NPIX   = CROPN * CROPN;          // 50176 = 196 * 256
constexpr float INV_SIGMA = 1e5f;              // 1/SIGMA
constexpr float INV_GAMMA = 1e5f;              // 1/GAMMA
constexpr float EPSV  = 1e-4f;                 // EPS
constexpr float NEARV = 0.1f;
constexpr float FARV  = 100.0f;
constexpr float INV_FMN = 1.0f / (FARV - NEARV);
constexpr float THRESH = 1.1512915464633e-04f; // SIGMA * ln(1/DIST_EPS - 1)
}

struct FaceGeom {
  bool  inside;
  bool  contrib;
  bool  valid;
  float d2min;
  float wc0, wc1, wc2;
  float zns;   // zn_safe
};

// sf: x,y,(1/z) per vertex (9 floats); sc: den_inv, inv_len2 for 3 edges (4 floats)
__device__ __forceinline__ FaceGeom face_geom(const float* __restrict__ fv,
                                              const float* __restrict__ fc,
                                              float qx, float qy) {
  float x0 = fv[0], y0 = fv[1], iz0 = fv[2];
  float x1 = fv[3], y1 = fv[4], iz1 = fv[5];
  float x2 = fv[6], y2 = fv[7], iz2 = fv[8];
  float den_inv = fc[0];
  float dqx2 = qx - x2, dqy2 = qy - y2;
  float w0 = ((y1 - y2) * dqx2 + (x2 - x1) * dqy2) * den_inv;
  float w1 = ((y2 - y0) * dqx2 + (x0 - x2) * dqy2) * den_inv;
  float w2 = 1.0f - w0 - w1;
  bool inside = (w0 >= 0.0f) && (w1 >= 0.0f) && (w2 >= 0.0f);

  float d2min;
  {
    float qax = qx - x0, qay = qy - y0;
    float ex = x1 - x0, ey = y1 - y0;
    float tt = fminf(fmaxf((qax * ex + qay * ey) * fc[1], 0.0f), 1.0f);
    float dx = qax - tt * ex, dy = qay - tt * ey;
    d2min = dx * dx + dy * dy;
  }
  {
    float qax = qx - x1, qay = qy - y1;
    float ex = x2 - x1, ey = y2 - y1;
    float tt = fminf(fmaxf((qax * ex + qay * ey) * fc[2], 0.0f), 1.0f);
    float dx = qax - tt * ex, dy = qay - tt * ey;
    d2min = fminf(d2min, dx * dx + dy * dy);
  }
  {
    float qax = qx - x2, qay = qy - y2;
    float ex = x0 - x2, ey = y0 - y2;
    float tt = fminf(fmaxf((qax * ex + qay * ey) * fc[3], 0.0f), 1.0f);
    float dx = qax - tt * ex, dy = qay - tt * ey;
    d2min = fminf(d2min, dx * dx + dy * dy);
  }

  bool contrib = inside || (d2min <= THRESH);

  float wc0 = fminf(fmaxf(w0, 0.0f), 1.0f);
  float wc1 = fminf(fmaxf(w1, 0.0f), 1.0f);
  float wc2 = fminf(fmaxf(w2, 0.0f), 1.0f);
  float inv_s = 1.0f / fmaxf(wc0 + wc1 + wc2, 1e-12f);
  wc0 *= inv_s; wc1 *= inv_s; wc2 *= inv_s;

  float zden = fmaxf(wc0 * iz0 + wc1 * iz1 + wc2 * iz2, 1e-12f);
  float zp = 1.0f / zden;
  bool valid = contrib && (zp >= NEARV) && (zp <= FARV);
  float zn = (FARV - zp) * INV_FMN;

  FaceGeom g;
  g.inside = inside; g.contrib = contrib; g.valid = valid;
  g.d2min = d2min;
  g.wc0 = wc0; g.wc1 = wc1; g.wc2 = wc2;
  g.zns = valid ? zn : 0.0f;
  return g;
}

__global__ __launch_bounds__(256) void softras_kernel(
    const float* __restrict__ g_faces, const float* __restrict__ g_tex,
    float* __restrict__ d_out) {
  __shared__ float sf[NFACES * 9];   // x,y,1/z per vertex
  __shared__ float st[NFACES * 9];   // texture (depth) values
  __shared__ float sc[NFACES * 4];   // den_inv, inv_len2 x3

  for (int i = threadIdx.x; i < NFACES * 9; i += 256) {
    sf[i] = g_faces[i];
    st[i] = g_tex[i];
  }
  __syncthreads();
  // replace z with 1/z (disjoint addresses vs. x,y reads below)
  for (int i = threadIdx.x; i < NFACES * 3; i += 256) {
    sf[i * 3 + 2] = 1.0f / sf[i * 3 + 2];
  }
  // per-face constants
  for (int f = threadIdx.x; f < NFACES; f += 256) {
    const float* fv = &sf[f * 9];
    float x0 = fv[0], y0 = fv[1];
    float x1 = fv[3], y1 = fv[4];
    float x2 = fv[6], y2 = fv[7];
    float den = (y1 - y2) * (x0 - x2) + (x2 - x1) * (y0 - y2);
    if (fabsf(den) < 1e-10f) den = (den < 0.0f) ? -1e-10f : 1e-10f;
    sc[f * 4 + 0] = 1.0f / den;
    float e;
    e = (x1 - x0) * (x1 - x0) + (y1 - y0) * (y1 - y0);
    sc[f * 4 + 1] = 1.0f / fmaxf(e, 1e-12f);
    e = (x2 - x1) * (x2 - x1) + (y2 - y1) * (y2 - y1);
    sc[f * 4 + 2] = 1.0f / fmaxf(e, 1e-12f);
    e = (x0 - x2) * (x0 - x2) + (y0 - y2) * (y0 - y2);
    sc[f * 4 + 3] = 1.0f / fmaxf(e, 1e-12f);
  }
  __syncthreads();

  int t = blockIdx.x * 256 + threadIdx.x;   // grid is exactly NPIX threads
  int row = t / CROPN, col = t - row * CROPN;
  float qx = (2.0f * (col + CROP0) + 1.0f) * (1.0f / IMG) - 1.0f;
  float qy = (2.0f * (IMG - 1 - (row + CROP0)) + 1.0f) * (1.0f / IMG) - 1.0f;

  // pass 1: zmax
  float zmax = EPSV;
  for (int f = 0; f < NFACES; ++f) {
    FaceGeom g = face_geom(&sf[f * 9], &sc[f * 4], qx, qy);
    zmax = fmaxf(zmax, g.zns);
  }

  // pass 2: accumulate
  float sum_ew = 0.0f, sum_r = 0.0f, sum_g = 0.0f, sum_b = 0.0f;
  float aprod = 1.0f;
  for (int f = 0; f < NFACES; ++f) {
    FaceGeom g = face_geom(&sf[f * 9], &sc[f * 4], qx, qy);
    float xx = (g.inside ? 1.0f : -1.0f) * g.d2min * INV_SIGMA;
    float e = expf(-fabsf(xx));
    float Dp = (xx >= 0.0f) ? (1.0f / (1.0f + e)) : (e / (1.0f + e));
    float ew = g.valid ? (Dp * expf((g.zns - zmax) * INV_GAMMA)) : 0.0f;
    const float* tx = &st[f * 9];
    sum_r += ew * (g.wc0 * tx[0] + g.wc1 * tx[3] + g.wc2 * tx[6]);
    sum_g += ew * (g.wc0 * tx[1] + g.wc1 * tx[4] + g.wc2 * tx[7]);
    sum_b += ew * (g.wc0 * tx[2] + g.wc1 * tx[5] + g.wc2 * tx[8]);
    sum_ew += ew;
    aprod *= g.contrib ? (1.0f - Dp) : 1.0f;
  }

  float bg = expf((EPSV - zmax) * INV_GAMMA);
  float inv_den = 1.0f / (sum_ew + bg);
  d_out[t] = 1.0f - aprod;                 // rendered_seg (alpha)
  float* dd = d_out + NPIX + t * 3;        // rendered_depth (rgb)
  dd[0] = sum_r * inv_den;
  dd[1] = sum_g * inv_den;
  dd[2] = sum_b * inv_den;
}

extern "C" void kernel_launch(void* const* d_in, const int* in_sizes, int n_in,
                              void* d_out, int out_size, void* d_ws, size_t ws_size,
                              hipStream_t stream) {
  const float* faces = (const float*)d_in[0];  // (1,384,3,3)
  const float* tex   = (const float*)d_in[1];  // (1,384,3,3)
  float* out = (float*)d_out;                  // 50176 seg + 150528 depth
  softras_kernel<<<NPIX / 256, 256, 0, stream>>>(faces, tex, out);
}

// Round 2
// 76.379 us; speedup vs baseline: 3.0765x; 3.0765x over previous
//
#include <hip/hip_runtime.h>
#include <math.h>

namespace {
constexpr int NFACES = 384;
constexpr int IMG    = 256;
constexpr int CROP0  = 16;
constexpr int CROPN  = 224;
constexpr int NPIX   = CROPN * CROPN;          // 50176
constexpr int REC    = 28;                     // floats per face record (16B aligned)
constexpr float INV_SIGMA = 1e5f;              // 1/SIGMA
constexpr float INV_GAMMA = 1e5f;              // 1/GAMMA
constexpr float EPSV  = 1e-4f;                 // EPS
constexpr float NEARV = 0.1f;
constexpr float FARV  = 100.0f;
constexpr float INV_FMN = 1.0f / (FARV - NEARV);
constexpr float THRESH = 1.1512915464633e-04f; // SIGMA * ln(1/DIST_EPS - 1)
}

__device__ __forceinline__ float clamp01(float x) {
  return fminf(fmaxf(x, 0.0f), 1.0f);
}

// Record layout (28 floats):
// 0-5:  x0,y0,x1,y1,x2,y2
// 6-8:  iz0,iz1,iz2            (1/z)
// 9-12: e01,e02,e11,e12        (barycentric coeffs premultiplied by 1/den)
// 13-15: il01,il12,il20        (1/edge_len^2 for edges v0->v1, v1->v2, v2->v0)
// 16-24: tex (3 verts x 3 ch)
// 25-27: pad
__global__ __launch_bounds__(512) void softras_kernel(
    const float* __restrict__ g_faces, const float* __restrict__ g_tex,
    float* __restrict__ d_out) {
  __shared__ __align__(16) float S[NFACES * REC];   // 43008 B

  int tid = threadIdx.x;
  if (tid < NFACES) {
    int f = tid;
    const float* gv = g_faces + f * 9;
    float x0 = gv[0], y0 = gv[1], z0 = gv[2];
    float x1 = gv[3], y1 = gv[4], z1 = gv[5];
    float x2 = gv[6], y2 = gv[7], z2 = gv[8];
    float* r = &S[f * REC];
    r[0] = x0; r[1] = y0; r[2] = x1; r[3] = y1; r[4] = x2; r[5] = y2;
    r[6] = 1.0f / z0; r[7] = 1.0f / z1; r[8] = 1.0f / z2;
    float den = (y1 - y2) * (x0 - x2) + (x2 - x1) * (y0 - y2);
    if (fabsf(den) < 1e-10f) den = (den < 0.0f) ? -1e-10f : 1e-10f;
    float dinv = 1.0f / den;
    r[9]  = (y1 - y2) * dinv;
    r[10] = (x2 - x1) * dinv;
    r[11] = (y2 - y0) * dinv;
    r[12] = (x0 - x2) * dinv;
    float e;
    e = (x1 - x0) * (x1 - x0) + (y1 - y0) * (y1 - y0);
    r[13] = 1.0f / fmaxf(e, 1e-12f);
    e = (x2 - x1) * (x2 - x1) + (y2 - y1) * (y2 - y1);
    r[14] = 1.0f / fmaxf(e, 1e-12f);
    e = (x0 - x2) * (x0 - x2) + (y0 - y2) * (y0 - y2);
    r[15] = 1.0f / fmaxf(e, 1e-12f);
    const float* gt = g_tex + f * 9;
    #pragma unroll
    for (int k = 0; k < 9; ++k) r[16 + k] = gt[k];
    r[25] = 0.0f; r[26] = 0.0f; r[27] = 0.0f;
  }
  __syncthreads();

  int w    = tid >> 6;           // wave id in block (0..7)
  int lane = tid & 63;
  int s    = lane >> 3;          // face chunk (0..7)
  int p    = lane & 7;           // pixel within wave (0..7)
  int t    = blockIdx.x * 64 + w * 8 + p;   // global pixel (grid covers NPIX exactly)

  int row = t / CROPN, col = t - row * CROPN;
  float qx = (2.0f * (col + CROP0) + 1.0f) * (1.0f / IMG) - 1.0f;
  float qy = (2.0f * (IMG - 1 - (row + CROP0)) + 1.0f) * (1.0f / IMG) - 1.0f;

  float m = EPSV;          // running zmax (EPS floor, matches ref)
  float sum_ew = 0.0f, sum_r = 0.0f, sum_g = 0.0f, sum_b = 0.0f;
  float aprod = 1.0f;

  for (int i = 0; i < NFACES / 8; ++i) {
    int f = i * 8 + s;
    const float4* R = reinterpret_cast<const float4*>(&S[f * REC]);
    float4 A  = R[0];  // x0,y0,x1,y1
    float4 B  = R[1];  // x2,y2,iz0,iz1
    float4 C  = R[2];  // iz2,e01,e02,e11
    float4 D  = R[3];  // e12,il01,il12,il20
    float4 T0 = R[4];  // t00,t01,t02,t10
    float4 T1 = R[5];  // t11,t12,t20,t21
    float4 T2 = R[6];  // t22,pad,pad,pad

    float qa0x = qx - A.x, qa0y = qy - A.y;
    float qa1x = qx - A.z, qa1y = qy - A.w;
    float qa2x = qx - B.x, qa2y = qy - B.y;

    float w0 = C.y * qa2x + C.z * qa2y;
    float w1 = C.w * qa2x + D.x * qa2y;
    float w2 = 1.0f - w0 - w1;
    bool inside = (w0 >= 0.0f) && (w1 >= 0.0f) && (w2 >= 0.0f);

    float ex = qa0x - qa1x, ey = qa0y - qa1y;
    float tt = clamp01((qa0x * ex + qa0y * ey) * D.y);
    float dx = qa0x - tt * ex, dy = qa0y - tt * ey;
    float d2min = dx * dx + dy * dy;

    ex = qa1x - qa2x; ey = qa1y - qa2y;
    tt = clamp01((qa1x * ex + qa1y * ey) * D.z);
    dx = qa1x - tt * ex; dy = qa1y - tt * ey;
    d2min = fminf(d2min, dx * dx + dy * dy);

    ex = qa2x - qa0x; ey = qa2y - qa0y;
    tt = clamp01((qa2x * ex + qa2y * ey) * D.w);
    dx = qa2x - tt * ex; dy = qa2y - tt * ey;
    d2min = fminf(d2min, dx * dx + dy * dy);

    bool contrib = inside || (d2min <= THRESH);

    float wc0 = clamp01(w0), wc1 = clamp01(w1), wc2 = clamp01(w2);
    float invs = __builtin_amdgcn_rcpf(fmaxf(wc0 + wc1 + wc2, 1e-12f));
    wc0 *= invs; wc1 *= invs; wc2 *= invs;

    float zden = fmaxf(wc0 * B.z + wc1 * B.w + wc2 * C.x, 1e-12f);
    float zp = 1.0f / zden;                 // precise div: feeds exp(x*1e5)
    bool valid = contrib && (zp >= NEARV) && (zp <= FARV);
    float zn = (FARV - zp) * INV_FMN;
    float zns = valid ? zn : 0.0f;

    float e = __expf(-d2min * INV_SIGMA);   // exp(-|sgn*d2min|/sigma)
    float r1pe = __builtin_amdgcn_rcpf(1.0f + e);
    float Dp = inside ? r1pe : e * r1pe;    // stable sigmoid

    float mnew = fmaxf(m, zns);
    float cor = __expf((m - mnew) * INV_GAMMA);
    float ew = valid ? Dp * __expf((zns - mnew) * INV_GAMMA) : 0.0f;

    float cr = wc0 * T0.x + wc1 * T0.w + wc2 * T1.z;
    float cg = wc0 * T0.y + wc1 * T1.x + wc2 * T1.w;
    float cb = wc0 * T0.z + wc1 * T1.y + wc2 * T2.x;

    sum_ew = sum_ew * cor + ew;
    sum_r  = sum_r  * cor + ew * cr;
    sum_g  = sum_g  * cor + ew * cg;
    sum_b  = sum_b  * cor + ew * cb;
    aprod *= contrib ? (1.0f - Dp) : 1.0f;
    m = mnew;
  }

  // merge the 8 face-chunks (lane bits 3..5): online-softmax merge + product
  #pragma unroll
  for (int mask = 8; mask <= 32; mask <<= 1) {
    float mo = __shfl_xor(m, mask);
    float so = __shfl_xor(sum_ew, mask);
    float ro = __shfl_xor(sum_r, mask);
    float go = __shfl_xor(sum_g, mask);
    float bo = __shfl_xor(sum_b, mask);
    float ao = __shfl_xor(aprod, mask);
    float mn = fmaxf(m, mo);
    float c1 = __expf((m - mn) * INV_GAMMA);
    float c2 = __expf((mo - mn) * INV_GAMMA);
    sum_ew = sum_ew * c1 + so * c2;
    sum_r  = sum_r  * c1 + ro * c2;
    sum_g  = sum_g  * c1 + go * c2;
    sum_b  = sum_b  * c1 + bo * c2;
    aprod *= ao;
    m = mn;
  }

  if (s == 0) {
    float bg = __expf((EPSV - m) * INV_GAMMA);
    float inv_den = 1.0f / (sum_ew + bg);
    d_out[t] = 1.0f - aprod;               // rendered_seg
    float* dd = d_out + NPIX + t * 3;      // rendered_depth (rgb)
    dd[0] = sum_r * inv_den;
    dd[1] = sum_g * inv_den;
    dd[2] = sum_b * inv_den;
  }
}

extern "C" void kernel_launch(void* const* d_in, const int* in_sizes, int n_in,
                              void* d_out, int out_size, void* d_ws, size_t ws_size,
                              hipStream_t stream) {
  const float* faces = (const float*)d_in[0];  // (1,384,3,3)
  const float* tex   = (const float*)d_in[1];  // (1,384,3,3)
  float* out = (float*)d_out;                  // 50176 seg + 150528 depth
  softras_kernel<<<NPIX * 8 / 512, 512, 0, stream>>>(faces, tex, out);
}

// Round 3
// 16.244 us; speedup vs baseline: 14.4651x; 4.7019x over previous
//
#include <hip/hip_runtime.h>
#include <math.h>

namespace {
constexpr int NFACES = 384;
constexpr int IMG    = 256;
constexpr int CROP0  = 16;
constexpr int CROPN  = 224;
constexpr int NPIX   = CROPN * CROPN;       // 50176
constexpr int TILE   = 8;                   // 8x8 pixel tiles
constexpr int TILES_X = CROPN / TILE;       // 28
constexpr int NTILES  = TILES_X * TILES_X;  // 784
constexpr int REC    = 28;                  // floats per face record (16B aligned)
constexpr int CAP    = 128;                 // staged faces per chunk
constexpr float INV_SIGMA = 1e5f;
constexpr float INV_GAMMA = 1e5f;
constexpr float EPSV  = 1e-4f;
constexpr float NEARV = 0.1f;
constexpr float FARV  = 100.0f;
constexpr float INV_FMN = 1.0f / (FARV - NEARV);
constexpr float THRESH = 1.1512915464633e-04f;  // SIGMA*ln(1/DIST_EPS - 1)
constexpr float RADIUS = 0.0118f;               // sqrt(THRESH) + safety margin
}

__device__ __forceinline__ float clamp01(float x) {
  return fminf(fmaxf(x, 0.0f), 1.0f);
}

// Record layout (28 floats):
// 0-5: x0,y0,x1,y1,x2,y2 | 6-8: iz0,iz1,iz2 | 9-12: bary coeffs * 1/den
// 13-15: 1/len^2 edges (01,12,20) | 16-24: tex | 25-27: pad
__global__ __launch_bounds__(256) void softras_tiled(
    const float* __restrict__ g_faces, const float* __restrict__ g_tex,
    float* __restrict__ d_out) {
  __shared__ __align__(16) float srec[CAP * REC];   // 14336 B
  __shared__ unsigned short slist[NFACES];
  __shared__ int scnt[4];

  int tid  = threadIdx.x;
  int w    = tid >> 6;
  int lane = tid & 63;

  int tileX = blockIdx.x % TILES_X;
  int tileY = blockIdx.x / TILES_X;
  // NDC bounds of this tile's pixel centers
  float x_lo = (2.0f * (tileX * TILE + CROP0) + 1.0f) * (1.0f / IMG) - 1.0f;
  float x_hi = x_lo + (TILE - 1) * (2.0f / IMG);
  float y_hi = (2.0f * (IMG - 1 - (tileY * TILE + CROP0)) + 1.0f) * (1.0f / IMG) - 1.0f;
  float y_lo = y_hi - (TILE - 1) * (2.0f / IMG);

  // ---- Phase 1: deterministic binning (ordered ballot compaction) ----
  int base = 0;
  for (int r = 0; r < 2; ++r) {
    int f = r * 256 + tid;
    bool pred = false;
    if (f < NFACES) {
      const float* gv = g_faces + f * 9;
      float fx0 = gv[0], fy0 = gv[1];
      float fx1 = gv[3], fy1 = gv[4];
      float fx2 = gv[6], fy2 = gv[7];
      float bxmin = fminf(fx0, fminf(fx1, fx2)) - RADIUS;
      float bxmax = fmaxf(fx0, fmaxf(fx1, fx2)) + RADIUS;
      float bymin = fminf(fy0, fminf(fy1, fy2)) - RADIUS;
      float bymax = fmaxf(fy0, fmaxf(fy1, fy2)) + RADIUS;
      pred = (bxmin <= x_hi) && (bxmax >= x_lo) && (bymin <= y_hi) && (bymax >= y_lo);
    }
    unsigned long long bal = __ballot(pred);
    int wpre = __popcll(bal & ((1ull << lane) - 1ull));
    if (lane == 0) scnt[w] = __popcll(bal);
    __syncthreads();
    int off = base;
    for (int i = 0; i < w; ++i) off += scnt[i];
    if (pred) slist[off + wpre] = (unsigned short)f;
    base += scnt[0] + scnt[1] + scnt[2] + scnt[3];
    __syncthreads();
  }
  const int L = base;

  // ---- Phase 2: per-pixel accumulation over listed faces ----
  int s  = lane >> 4;                 // face sub-chunk 0..3
  int p  = (w << 4) + (lane & 15);    // pixel in tile 0..63
  int px = p & 7, py = p >> 3;
  float qx = x_lo + px * (2.0f / IMG);
  float qy = y_hi - py * (2.0f / IMG);

  float m = EPSV;
  float sum_ew = 0.0f, sum_r = 0.0f, sum_g = 0.0f, sum_b = 0.0f;
  float aprod = 1.0f;

  for (int c = 0; c < L; c += CAP) {
    int n = min(CAP, L - c);
    // stage records for this chunk (recompute derived per-face constants)
    for (int k = tid; k < n; k += 256) {
      int f = slist[c + k];
      const float* gv = g_faces + f * 9;
      const float* gt = g_tex + f * 9;
      float x0 = gv[0], y0 = gv[1], z0 = gv[2];
      float x1 = gv[3], y1 = gv[4], z1 = gv[5];
      float x2 = gv[6], y2 = gv[7], z2 = gv[8];
      float den = (y1 - y2) * (x0 - x2) + (x2 - x1) * (y0 - y2);
      if (fabsf(den) < 1e-10f) den = (den < 0.0f) ? -1e-10f : 1e-10f;
      float dinv = 1.0f / den;
      float e01 = (x1 - x0) * (x1 - x0) + (y1 - y0) * (y1 - y0);
      float e12 = (x2 - x1) * (x2 - x1) + (y2 - y1) * (y2 - y1);
      float e20 = (x0 - x2) * (x0 - x2) + (y0 - y2) * (y0 - y2);
      float4* R = reinterpret_cast<float4*>(&srec[k * REC]);
      R[0] = make_float4(x0, y0, x1, y1);
      R[1] = make_float4(x2, y2, 1.0f / z0, 1.0f / z1);
      R[2] = make_float4(1.0f / z2, (y1 - y2) * dinv, (x2 - x1) * dinv,
                         (y2 - y0) * dinv);
      R[3] = make_float4((x0 - x2) * dinv, 1.0f / fmaxf(e01, 1e-12f),
                         1.0f / fmaxf(e12, 1e-12f), 1.0f / fmaxf(e20, 1e-12f));
      R[4] = make_float4(gt[0], gt[1], gt[2], gt[3]);
      R[5] = make_float4(gt[4], gt[5], gt[6], gt[7]);
      R[6] = make_float4(gt[8], 0.0f, 0.0f, 0.0f);
    }
    __syncthreads();

    for (int j = s; j < n; j += 4) {
      const float4* R = reinterpret_cast<const float4*>(&srec[j * REC]);
      float4 A  = R[0];  // x0,y0,x1,y1
      float4 B  = R[1];  // x2,y2,iz0,iz1
      float4 C  = R[2];  // iz2,e01,e02,e11
      float4 D  = R[3];  // e12,il01,il12,il20
      float4 T0 = R[4];
      float4 T1 = R[5];
      float4 T2 = R[6];

      float qa0x = qx - A.x, qa0y = qy - A.y;
      float qa1x = qx - A.z, qa1y = qy - A.w;
      float qa2x = qx - B.x, qa2y = qy - B.y;

      float w0 = C.y * qa2x + C.z * qa2y;
      float w1 = C.w * qa2x + D.x * qa2y;
      float w2 = 1.0f - w0 - w1;
      bool inside = (w0 >= 0.0f) && (w1 >= 0.0f) && (w2 >= 0.0f);

      float ex = qa0x - qa1x, ey = qa0y - qa1y;
      float tt = clamp01((qa0x * ex + qa0y * ey) * D.y);
      float dx = qa0x - tt * ex, dy = qa0y - tt * ey;
      float d2min = dx * dx + dy * dy;

      ex = qa1x - qa2x; ey = qa1y - qa2y;
      tt = clamp01((qa1x * ex + qa1y * ey) * D.z);
      dx = qa1x - tt * ex; dy = qa1y - tt * ey;
      d2min = fminf(d2min, dx * dx + dy * dy);

      ex = qa2x - qa0x; ey = qa2y - qa0y;
      tt = clamp01((qa2x * ex + qa2y * ey) * D.w);
      dx = qa2x - tt * ex; dy = qa2y - tt * ey;
      d2min = fminf(d2min, dx * dx + dy * dy);

      bool contrib = inside || (d2min <= THRESH);

      float wc0 = clamp01(w0), wc1 = clamp01(w1), wc2 = clamp01(w2);
      float invs = __builtin_amdgcn_rcpf(fmaxf(wc0 + wc1 + wc2, 1e-12f));
      wc0 *= invs; wc1 *= invs; wc2 *= invs;

      float zden = fmaxf(wc0 * B.z + wc1 * B.w + wc2 * C.x, 1e-12f);
      float zp = 1.0f / zden;   // precise: feeds exp(x*1e5)
      bool valid = contrib && (zp >= NEARV) && (zp <= FARV);
      float zn = (FARV - zp) * INV_FMN;
      float zns = valid ? zn : 0.0f;

      float e = __expf(-d2min * INV_SIGMA);
      float r1pe = __builtin_amdgcn_rcpf(1.0f + e);
      float Dp = inside ? r1pe : e * r1pe;  // stable sigmoid

      float mnew = fmaxf(m, zns);
      float cor = __expf((m - mnew) * INV_GAMMA);
      float ew = valid ? Dp * __expf((zns - mnew) * INV_GAMMA) : 0.0f;

      float cr = wc0 * T0.x + wc1 * T0.w + wc2 * T1.z;
      float cg = wc0 * T0.y + wc1 * T1.x + wc2 * T1.w;
      float cb = wc0 * T0.z + wc1 * T1.y + wc2 * T2.x;

      sum_ew = sum_ew * cor + ew;
      sum_r  = sum_r  * cor + ew * cr;
      sum_g  = sum_g  * cor + ew * cg;
      sum_b  = sum_b  * cor + ew * cb;
      aprod *= contrib ? (1.0f - Dp) : 1.0f;
      m = mnew;
    }
    __syncthreads();   // protect srec before next chunk's staging
  }

  // ---- merge the 4 face sub-chunks (lane bits 4..5) ----
  #pragma unroll
  for (int mask = 16; mask <= 32; mask <<= 1) {
    float mo = __shfl_xor(m, mask);
    float so = __shfl_xor(sum_ew, mask);
    float ro = __shfl_xor(sum_r, mask);
    float go = __shfl_xor(sum_g, mask);
    float bo = __shfl_xor(sum_b, mask);
    float ao = __shfl_xor(aprod, mask);
    float mn = fmaxf(m, mo);
    float c1 = __expf((m - mn) * INV_GAMMA);
    float c2 = __expf((mo - mn) * INV_GAMMA);
    sum_ew = sum_ew * c1 + so * c2;
    sum_r  = sum_r  * c1 + ro * c2;
    sum_g  = sum_g  * c1 + go * c2;
    sum_b  = sum_b  * c1 + bo * c2;
    aprod *= ao;
    m = mn;
  }

  if (s == 0) {
    int row = tileY * TILE + py;
    int col = tileX * TILE + px;
    int t = row * CROPN + col;
    float bg = __expf((EPSV - m) * INV_GAMMA);
    float inv_den = 1.0f / (sum_ew + bg);
    d_out[t] = 1.0f - aprod;               // rendered_seg
    float* dd = d_out + NPIX + t * 3;      // rendered_depth
    dd[0] = sum_r * inv_den;
    dd[1] = sum_g * inv_den;
    dd[2] = sum_b * inv_den;
  }
}

extern "C" void kernel_launch(void* const* d_in, const int* in_sizes, int n_in,
                              void* d_out, int out_size, void* d_ws, size_t ws_size,
                              hipStream_t stream) {
  const float* faces = (const float*)d_in[0];  // (1,384,3,3)
  const float* tex   = (const float*)d_in[1];  // (1,384,3,3)
  float* out = (float*)d_out;                  // 50176 seg + 150528 depth
  softras_tiled<<<NTILES, 256, 0, stream>>>(faces, tex, out);
}